// Round 7
// baseline (682.389 us; speedup 1.0000x reference)
//
#include <hip/hip_runtime.h>

constexpr int N_NODES = 50000;
constexpr int N_EDGES = 800000;
constexpr float BN_EPS = 1e-5f;
constexpr int BNA_BLOCKS = 256;

typedef __attribute__((ext_vector_type(8))) short short8;
typedef __attribute__((ext_vector_type(4))) float f32x4;

__device__ __forceinline__ float bf2f(ushort u) {
  union { uint i; float f; } v;
  v.i = ((uint)u) << 16;
  return v.f;
}
__device__ __forceinline__ ushort f2bf(float f) {
  union { float f; uint i; } v;
  v.f = f;
  uint r = v.i + 0x7fff + ((v.i >> 16) & 1);  // RNE
  return (ushort)(r >> 16);
}

// ---------------- degree / normalization ----------------
__global__ void k_deg(const int* __restrict__ row, int* __restrict__ deg) {
  int i = blockIdx.x * blockDim.x + threadIdx.x;
  int stride = gridDim.x * blockDim.x;
  for (; i < N_EDGES; i += stride) atomicAdd(&deg[row[i]], 1);
}

__global__ void k_disqrt(const int* __restrict__ deg, float* __restrict__ dis) {
  int i = blockIdx.x * blockDim.x + threadIdx.x;
  if (i < N_NODES) dis[i] = rsqrtf((float)(deg[i] + 1));
}

// ---------------- CSR build: 3-phase scan + scatter ----------------
__global__ void k_scan_part(const int* __restrict__ deg, int* __restrict__ bsum) {
  __shared__ int s[256];
  int t = threadIdx.x, i = blockIdx.x * 256 + t;
  s[t] = (i < N_NODES) ? deg[i] : 0;
  __syncthreads();
  for (int off = 128; off > 0; off >>= 1) {
    if (t < off) s[t] += s[t + off];
    __syncthreads();
  }
  if (t == 0) bsum[blockIdx.x] = s[0];
}

__global__ void k_scan_top(const int* __restrict__ bsum, int* __restrict__ boff, int nb) {
  __shared__ int s[256];
  int t = threadIdx.x;
  int v = (t < nb) ? bsum[t] : 0;
  s[t] = v;
  __syncthreads();
  for (int off = 1; off < 256; off <<= 1) {
    int x = (t >= off) ? s[t - off] : 0;
    __syncthreads();
    s[t] += x;
    __syncthreads();
  }
  if (t < nb) boff[t] = s[t] - v;  // exclusive
}

__global__ void k_scan_final(const int* __restrict__ deg, const int* __restrict__ boff,
                             int* __restrict__ row_start) {
  __shared__ int s[256];
  int t = threadIdx.x, i = blockIdx.x * 256 + t;
  int v = (i < N_NODES) ? deg[i] : 0;
  s[t] = v;
  __syncthreads();
  for (int off = 1; off < 256; off <<= 1) {
    int x = (t >= off) ? s[t - off] : 0;
    __syncthreads();
    s[t] += x;
    __syncthreads();
  }
  if (i < N_NODES) row_start[i] = boff[blockIdx.x] + s[t] - v;
  if (i == 0) row_start[N_NODES] = N_EDGES;
}

__global__ void k_scatter(const int* __restrict__ row, const int* __restrict__ col,
                          const int* __restrict__ row_start, int* __restrict__ fill,
                          int* __restrict__ col_sorted) {
  int i = blockIdx.x * blockDim.x + threadIdx.x;
  int stride = gridDim.x * blockDim.x;
  for (; i < N_EDGES; i += stride) {
    int r = row[i];
    int pos = row_start[r] + atomicAdd(&fill[r], 1);
    col_sorted[pos] = col[i];
  }
}

// ---------------- W transpose to bf16: Wt[n][k] = bf16(W[k][n]) ----------------
__global__ void k_wt(const float* __restrict__ W, ushort* __restrict__ Wt, int K, int N) {
  int idx = blockIdx.x * 256 + threadIdx.x;
  if (idx >= K * N) return;
  int n = idx / K, k = idx % K;
  Wt[idx] = f2bf(W[(size_t)k * N + n]);
}

// ---------------- bf16 MFMA GEMM: hsc = bf16( f(A) @ W * d_isqrt ), chunk-major ----
// APPLY_BN: A is bf16 [N,256], f(A)=relu(A*scale+shift). else A fp32 [N,256], f=id.
// Wt: [D,256] bf16. Output hsc: [D/CW][N_NODES][CW] (feature-chunk-major).
// BM=BN=128, BK=32, 256 threads = 4 waves (2x2), 64x64/wave, 4x4 mfma_16x16x32_bf16.
template <int D, int CW, bool APPLY_BN>
__global__ __launch_bounds__(256, 3) void k_gemm_bf16(const void* __restrict__ Av,
                                                      const ushort* __restrict__ Wt,
                                                      const float* __restrict__ ss,
                                                      const float* __restrict__ dis,
                                                      ushort* __restrict__ hsc) {
  constexpr int BM = 128, BN = 128, BK = 32, K = 256;
  constexpr int LDP = BK + 8;  // 40 bf16 (80B) stride: conflict-free b128 frags
  __shared__ ushort As[BM * LDP];
  __shared__ ushort Bs[BN * LDP];
  const int tid = threadIdx.x;
  const int lane = tid & 63;
  const int wid = tid >> 6;
  const int wr = wid >> 1, wc = wid & 1;  // 2x2 wave grid
  constexpr int NB = D / BN;
  const int rb = (blockIdx.x / NB) * BM;
  const int cb = (blockIdx.x % NB) * BN;

  f32x4 acc[4][4];
#pragma unroll
  for (int m = 0; m < 4; ++m)
#pragma unroll
    for (int n = 0; n < 4; ++n) acc[m][n] = (f32x4)(0.f);

  for (int kt = 0; kt < K; kt += BK) {
    // stage A: 128 rows x 32 k. 512 tasks of 8 elems.
#pragma unroll
    for (int it = 0; it < 2; ++it) {
      int idx = tid + it * 256;
      int row = idx >> 2, kq = idx & 3;
      int gr = rb + row;
      if (gr >= N_NODES) gr = N_NODES - 1;
      float e[8];
      if constexpr (APPLY_BN) {
        const ushort* A = (const ushort*)Av;
        short8 v = *reinterpret_cast<const short8*>(&A[(size_t)gr * K + kt + kq * 8]);
#pragma unroll
        for (int q = 0; q < 8; ++q) {
          int k = kt + kq * 8 + q;
          e[q] = fmaxf(bf2f((ushort)v[q]) * ss[k] + ss[256 + k], 0.f);
        }
      } else {
        const float* A = (const float*)Av;
        const float4* src = reinterpret_cast<const float4*>(&A[(size_t)gr * K + kt + kq * 8]);
        float4 v0 = src[0], v1 = src[1];
        e[0] = v0.x; e[1] = v0.y; e[2] = v0.z; e[3] = v0.w;
        e[4] = v1.x; e[5] = v1.y; e[6] = v1.z; e[7] = v1.w;
      }
      short8 pk;
#pragma unroll
      for (int q = 0; q < 8; ++q) pk[q] = (short)f2bf(e[q]);
      *reinterpret_cast<short8*>(&As[row * LDP + kq * 8]) = pk;
    }
    // stage B from Wt (already bf16, k-contiguous)
#pragma unroll
    for (int it = 0; it < 2; ++it) {
      int idx = tid + it * 256;
      int n = idx >> 2, kq = idx & 3;
      short8 v = *reinterpret_cast<const short8*>(&Wt[(size_t)(cb + n) * K + kt + kq * 8]);
      *reinterpret_cast<short8*>(&Bs[n * LDP + kq * 8]) = v;
    }
    __syncthreads();

    const int rl = lane & 15;
    const int kb = (lane >> 4) * 8;
    short8 af[4], bfr[4];
#pragma unroll
    for (int f = 0; f < 4; ++f) {
      af[f] = *reinterpret_cast<short8*>(&As[(wr * 64 + f * 16 + rl) * LDP + kb]);
      bfr[f] = *reinterpret_cast<short8*>(&Bs[(wc * 64 + f * 16 + rl) * LDP + kb]);
    }
#pragma unroll
    for (int m = 0; m < 4; ++m)
#pragma unroll
      for (int n = 0; n < 4; ++n)
        acc[m][n] = __builtin_amdgcn_mfma_f32_16x16x32_bf16(af[m], bfr[n], acc[m][n], 0, 0, 0);
    __syncthreads();
  }

  // epilogue: *dis[row], cvt bf16, store chunk-major. C frag: col=lane&15, row=(lane>>4)*4+j.
  const int cl = lane & 15;
  const int rq = lane >> 4;
#pragma unroll
  for (int m = 0; m < 4; ++m) {
    int rbase = rb + wr * 64 + m * 16 + rq * 4;
#pragma unroll
    for (int j = 0; j < 4; ++j) {
      int row = rbase + j;
      if (row >= N_NODES) continue;
      float di = dis[row];
#pragma unroll
      for (int n = 0; n < 4; ++n) {
        int col = cb + wc * 64 + n * 16 + cl;
        size_t addr = ((size_t)(col / CW) * N_NODES + row) * CW + (col % CW);
        hsc[addr] = f2bf(acc[m][n][j] * di);
      }
    }
  }
}

// ---------------- chunked aggregation: out = dis*(self+sum_nbr) + b ----------------
// hsc chunk-major [8][N][CW]; chunk = blockIdx%8 -> XCD affinity (round-robin
// dispatch), so each XCD's 4MB L2 holds its own 3.2MB (CW=32) chunk.
// Wave = 1 node. LPE=CW/2 lanes per edge (ushort2 each), EPW=64/LPE edges in flight.
template <int CW, bool OUT_F32, int OUTD>
__global__ __launch_bounds__(256) void k_agg_chunk(const ushort* __restrict__ hsc,
                                                   const int* __restrict__ cs,
                                                   const int* __restrict__ rs,
                                                   const float* __restrict__ dis,
                                                   const float* __restrict__ bias,
                                                   void* __restrict__ outp) {
  constexpr int LPE = CW / 2;
  constexpr int EPW = 64 / LPE;
  const int chunk = blockIdx.x & 7;
  const int node = (blockIdx.x >> 3) * 4 + (threadIdx.x >> 6);
  if (node >= N_NODES) return;
  const int lane = threadIdx.x & 63;
  const int k = lane & (LPE - 1);
  const int eslot = lane / LPE;
  const ushort* bc = hsc + (size_t)chunk * N_NODES * CW + k * 2;

  float a0 = 0.f, a1 = 0.f;
  if (eslot == 0) {
    ushort2 v = *reinterpret_cast<const ushort2*>(&bc[(size_t)node * CW]);
    a0 = bf2f(v.x);
    a1 = bf2f(v.y);
  }
  int s = rs[node], e = rs[node + 1];
  for (int b0 = s; b0 < e; b0 += 64) {
    int nav = min(64, e - b0);
    int idx = (b0 + lane < e) ? __builtin_nontemporal_load(&cs[b0 + lane]) : 0;
    int j = 0;
    for (; j + 2 * EPW <= nav; j += 2 * EPW) {
      int c0 = __shfl(idx, j + eslot);
      int c1 = __shfl(idx, j + EPW + eslot);
      ushort2 v0 = *reinterpret_cast<const ushort2*>(&bc[(size_t)c0 * CW]);
      ushort2 v1 = *reinterpret_cast<const ushort2*>(&bc[(size_t)c1 * CW]);
      a0 += bf2f(v0.x) + bf2f(v1.x);
      a1 += bf2f(v0.y) + bf2f(v1.y);
    }
    for (; j < nav; j += EPW) {
      int je = j + eslot;
      int c = __shfl(idx, je < nav ? je : nav - 1);
      if (je < nav) {
        ushort2 v = *reinterpret_cast<const ushort2*>(&bc[(size_t)c * CW]);
        a0 += bf2f(v.x);
        a1 += bf2f(v.y);
      }
    }
  }
#pragma unroll
  for (int off = LPE; off < 64; off <<= 1) {
    a0 += __shfl_xor(a0, off);
    a1 += __shfl_xor(a1, off);
  }
  if (eslot == 0) {
    float di = dis[node];
    float2 b = *reinterpret_cast<const float2*>(&bias[chunk * CW + k * 2]);
    float o0 = a0 * di + b.x, o1 = a1 * di + b.y;
    if constexpr (OUT_F32) {
      float* out = (float*)outp;
      float2 o = {o0, o1};
      *reinterpret_cast<float2*>(&out[(size_t)node * OUTD + chunk * CW + k * 2]) = o;
    } else {
      ushort* out = (ushort*)outp;
      ushort2 o;
      o.x = f2bf(o0);
      o.y = f2bf(o1);
      *reinterpret_cast<ushort2*>(&out[(size_t)node * OUTD + chunk * CW + k * 2]) = o;
    }
  }
}

// ---------------- log_softmax over D=128 f32 logits (wave per node) ----------------
__global__ __launch_bounds__(256) void k_lsm(const float* __restrict__ pre2,
                                             float* __restrict__ out) {
  int node = (blockIdx.x * 256 + threadIdx.x) >> 6;
  if (node >= N_NODES) return;
  int lane = threadIdx.x & 63;
  float2 v = *reinterpret_cast<const float2*>(&pre2[(size_t)node * 128 + lane * 2]);
  float m = fmaxf(v.x, v.y);
#pragma unroll
  for (int o = 1; o < 64; o <<= 1) m = fmaxf(m, __shfl_xor(m, o));
  float sum = __expf(v.x - m) + __expf(v.y - m);
#pragma unroll
  for (int o = 1; o < 64; o <<= 1) sum += __shfl_xor(sum, o);
  float ls = m + logf(sum);
  float2 o2 = {v.x - ls, v.y - ls};
  *reinterpret_cast<float2*>(&out[(size_t)node * 128 + lane * 2]) = o2;
}

// ---------------- batchnorm stats: three-phase, atomic-free ----------------
__global__ __launch_bounds__(256) void k_bnstatsA(const ushort* __restrict__ pre,
                                                  float* __restrict__ partial) {
  int t = threadIdx.x;
  int rsub = t >> 7;
  int cp = (t & 127) * 2;
  float s0 = 0.f, s1 = 0.f, q0 = 0.f, q1 = 0.f;
  for (int r = blockIdx.x * 2 + rsub; r < N_NODES; r += BNA_BLOCKS * 2) {
    ushort2 v = *reinterpret_cast<const ushort2*>(&pre[(size_t)r * 256 + cp]);
    float f0 = bf2f(v.x), f1 = bf2f(v.y);
    s0 += f0;
    q0 += f0 * f0;
    s1 += f1;
    q1 += f1 * f1;
  }
  __shared__ float lsum[256], lsq[256];
  if (rsub) {
    lsum[cp] = s0;
    lsum[cp + 1] = s1;
    lsq[cp] = q0;
    lsq[cp + 1] = q1;
  }
  __syncthreads();
  if (!rsub) {
    float* p = &partial[(size_t)blockIdx.x * 512];
    p[cp] = s0 + lsum[cp];
    p[cp + 1] = s1 + lsum[cp + 1];
    p[256 + cp] = q0 + lsq[cp];
    p[256 + cp + 1] = q1 + lsq[cp + 1];
  }
}

__global__ __launch_bounds__(512) void k_bnstatsB(const float* __restrict__ partial,
                                                  float* __restrict__ p2) {
  int t = threadIdx.x, b = blockIdx.x;
  float a = 0.f;
#pragma unroll 8
  for (int r = 0; r < BNA_BLOCKS / 8; ++r)
    a += partial[(size_t)(b * (BNA_BLOCKS / 8) + r) * 512 + t];
  p2[(size_t)b * 512 + t] = a;
}

__global__ void k_bnfinal(const float* __restrict__ p2, const float* __restrict__ gamma,
                          const float* __restrict__ beta, float* __restrict__ ss) {
  int t = threadIdx.x;
  float sum = 0.f, sq = 0.f;
#pragma unroll
  for (int b = 0; b < 8; ++b) {
    sum += p2[(size_t)b * 512 + t];
    sq += p2[(size_t)b * 512 + 256 + t];
  }
  float mu = sum * (1.f / N_NODES);
  float var = sq * (1.f / N_NODES) - mu * mu;
  float sc = gamma[t] * rsqrtf(var + BN_EPS);
  ss[t] = sc;
  ss[256 + t] = beta[t] - mu * sc;
}

// ---------------- launcher ----------------
extern "C" void kernel_launch(void* const* d_in, const int* in_sizes, int n_in,
                              void* d_out, int out_size, void* d_ws, size_t ws_size,
                              hipStream_t stream) {
  const float* x = (const float*)d_in[0];
  const int* erow = (const int*)d_in[1];
  const int* ecol = erow + N_EDGES;
  const float* W0 = (const float*)d_in[2];
  const float* b0 = (const float*)d_in[3];
  const float* W1 = (const float*)d_in[4];
  const float* b1 = (const float*)d_in[5];
  const float* W2 = (const float*)d_in[6];
  const float* b2 = (const float*)d_in[7];
  const float* g0 = (const float*)d_in[8];
  const float* be0 = (const float*)d_in[9];
  const float* g1 = (const float*)d_in[10];
  const float* be1 = (const float*)d_in[11];
  float* out = (float*)d_out;

  char* ws = (char*)d_ws;
  size_t off = 0;
  auto take = [&](size_t bytes) {
    char* p = ws + off;
    off = (off + bytes + 255) & ~(size_t)255;
    return p;
  };
  int* deg = (int*)take(N_NODES * 4);
  int* fill = (int*)take(N_NODES * 4);
  size_t zero_bytes = off;  // deg+fill must start at 0 each call
  float* bnpart = (float*)take((size_t)BNA_BLOCKS * 512 * 4);
  float* bnpart2 = (float*)take(8 * 512 * 4);
  float* dis = (float*)take(N_NODES * 4);
  int* row_start = (int*)take((N_NODES + 1) * 4);
  int* bsum = (int*)take(256 * 4);
  int* boff = (int*)take(256 * 4);
  float* ss0 = (float*)take(512 * 4);
  float* ss1 = (float*)take(512 * 4);
  ushort* Wt0 = (ushort*)take(256 * 256 * 2);
  ushort* Wt1 = (ushort*)take(256 * 256 * 2);
  ushort* Wt2 = (ushort*)take(256 * 128 * 2);
  int* col_sorted = (int*)take((size_t)N_EDGES * 4);
  ushort* hsc = (ushort*)take((size_t)N_NODES * 256 * 2);   // chunk-major
  ushort* pre = (ushort*)take((size_t)N_NODES * 256 * 2);   // row-major bf16
  float* pre2 = (float*)take((size_t)N_NODES * 128 * 4);    // f32 logits
  if (off > ws_size) return;

  hipMemsetAsync(d_ws, 0, zero_bytes, stream);

  k_deg<<<1024, 256, 0, stream>>>(erow, deg);
  k_disqrt<<<(N_NODES + 255) / 256, 256, 0, stream>>>(deg, dis);
  int nb = (N_NODES + 255) / 256;  // 196
  k_scan_part<<<nb, 256, 0, stream>>>(deg, bsum);
  k_scan_top<<<1, 256, 0, stream>>>(bsum, boff, nb);
  k_scan_final<<<nb, 256, 0, stream>>>(deg, boff, row_start);
  k_scatter<<<1024, 256, 0, stream>>>(erow, ecol, row_start, fill, col_sorted);

  k_wt<<<(256 * 256 + 255) / 256, 256, 0, stream>>>(W0, Wt0, 256, 256);
  k_wt<<<(256 * 256 + 255) / 256, 256, 0, stream>>>(W1, Wt1, 256, 256);
  k_wt<<<(256 * 128 + 255) / 256, 256, 0, stream>>>(W2, Wt2, 256, 128);

  int mblocks = (N_NODES + 127) / 128;        // 391
  int aggc_grid = (N_NODES / 4) * 8;          // 100000
  int lsm_grid = (N_NODES * 64 + 255) / 256;  // 12500
  // layer 0
  k_gemm_bf16<256, 32, false><<<mblocks * 2, 256, 0, stream>>>(x, Wt0, nullptr, dis, hsc);
  k_agg_chunk<32, false, 256><<<aggc_grid, 256, 0, stream>>>(hsc, col_sorted, row_start, dis, b0, pre);
  k_bnstatsA<<<BNA_BLOCKS, 256, 0, stream>>>(pre, bnpart);
  k_bnstatsB<<<8, 512, 0, stream>>>(bnpart, bnpart2);
  k_bnfinal<<<1, 256, 0, stream>>>(bnpart2, g0, be0, ss0);
  // layer 1
  k_gemm_bf16<256, 32, true><<<mblocks * 2, 256, 0, stream>>>(pre, Wt1, ss0, dis, hsc);
  k_agg_chunk<32, false, 256><<<aggc_grid, 256, 0, stream>>>(hsc, col_sorted, row_start, dis, b1, pre);
  k_bnstatsA<<<BNA_BLOCKS, 256, 0, stream>>>(pre, bnpart);
  k_bnstatsB<<<8, 512, 0, stream>>>(bnpart, bnpart2);
  k_bnfinal<<<1, 256, 0, stream>>>(bnpart2, g1, be1, ss1);
  // layer 2: GEMM -> chunked agg (f32 logits) -> log_softmax
  k_gemm_bf16<128, 16, true><<<mblocks, 256, 0, stream>>>(pre, Wt2, ss1, dis, hsc);
  k_agg_chunk<16, true, 128><<<aggc_grid, 256, 0, stream>>>(hsc, col_sorted, row_start, dis, b2, pre2);
  k_lsm<<<lsm_grid, 256, 0, stream>>>(pre2, out);
}

// Round 8
// 678.379 us; speedup vs baseline: 1.0059x; 1.0059x over previous
//
#include <hip/hip_runtime.h>

constexpr int N_NODES = 50000;
constexpr int N_EDGES = 800000;
constexpr float BN_EPS = 1e-5f;
constexpr int BNA_BLOCKS = 256;

typedef __attribute__((ext_vector_type(8))) short short8;
typedef __attribute__((ext_vector_type(4))) float f32x4;

__device__ __forceinline__ float bf2f(ushort u) {
  union { uint i; float f; } v;
  v.i = ((uint)u) << 16;
  return v.f;
}
__device__ __forceinline__ ushort f2bf(float f) {
  union { float f; uint i; } v;
  v.f = f;
  uint r = v.i + 0x7fff + ((v.i >> 16) & 1);  // RNE
  return (ushort)(r >> 16);
}

// ---------------- degree / normalization ----------------
__global__ void k_deg(const int* __restrict__ row, int* __restrict__ deg) {
  int i = blockIdx.x * blockDim.x + threadIdx.x;
  int stride = gridDim.x * blockDim.x;
  for (; i < N_EDGES; i += stride) atomicAdd(&deg[row[i]], 1);
}

__global__ void k_disqrt(const int* __restrict__ deg, float* __restrict__ dis) {
  int i = blockIdx.x * blockDim.x + threadIdx.x;
  if (i < N_NODES) dis[i] = rsqrtf((float)(deg[i] + 1));
}

// ---------------- CSR build: 3-phase scan + scatter ----------------
__global__ void k_scan_part(const int* __restrict__ deg, int* __restrict__ bsum) {
  __shared__ int s[256];
  int t = threadIdx.x, i = blockIdx.x * 256 + t;
  s[t] = (i < N_NODES) ? deg[i] : 0;
  __syncthreads();
  for (int off = 128; off > 0; off >>= 1) {
    if (t < off) s[t] += s[t + off];
    __syncthreads();
  }
  if (t == 0) bsum[blockIdx.x] = s[0];
}

__global__ void k_scan_top(const int* __restrict__ bsum, int* __restrict__ boff, int nb) {
  __shared__ int s[256];
  int t = threadIdx.x;
  int v = (t < nb) ? bsum[t] : 0;
  s[t] = v;
  __syncthreads();
  for (int off = 1; off < 256; off <<= 1) {
    int x = (t >= off) ? s[t - off] : 0;
    __syncthreads();
    s[t] += x;
    __syncthreads();
  }
  if (t < nb) boff[t] = s[t] - v;  // exclusive
}

__global__ void k_scan_final(const int* __restrict__ deg, const int* __restrict__ boff,
                             int* __restrict__ row_start) {
  __shared__ int s[256];
  int t = threadIdx.x, i = blockIdx.x * 256 + t;
  int v = (i < N_NODES) ? deg[i] : 0;
  s[t] = v;
  __syncthreads();
  for (int off = 1; off < 256; off <<= 1) {
    int x = (t >= off) ? s[t - off] : 0;
    __syncthreads();
    s[t] += x;
    __syncthreads();
  }
  if (i < N_NODES) row_start[i] = boff[blockIdx.x] + s[t] - v;
  if (i == 0) row_start[N_NODES] = N_EDGES;
}

__global__ void k_scatter(const int* __restrict__ row, const int* __restrict__ col,
                          const int* __restrict__ row_start, int* __restrict__ fill,
                          int* __restrict__ col_sorted) {
  int i = blockIdx.x * blockDim.x + threadIdx.x;
  int stride = gridDim.x * blockDim.x;
  for (; i < N_EDGES; i += stride) {
    int r = row[i];
    int pos = row_start[r] + atomicAdd(&fill[r], 1);
    col_sorted[pos] = col[i];
  }
}

// ---------------- W transpose to bf16: Wt[n][k] = bf16(W[k][n]) ----------------
__global__ void k_wt(const float* __restrict__ W, ushort* __restrict__ Wt, int K, int N) {
  int idx = blockIdx.x * 256 + threadIdx.x;
  if (idx >= K * N) return;
  int n = idx / K, k = idx % K;
  Wt[idx] = f2bf(W[(size_t)k * N + n]);
}

// ---------------- bf16 MFMA GEMM: hsc = bf16( f(A) @ W * d_isqrt ), chunk-major ----
// APPLY_BN: A is bf16 [N,256], f(A)=relu(A*scale+shift). else A fp32 [N,256], f=id.
// Wt: [D,256] bf16. Output hsc: [D/CW][N_NODES][CW] (feature-chunk-major).
template <int D, int CW, bool APPLY_BN>
__global__ __launch_bounds__(256, 3) void k_gemm_bf16(const void* __restrict__ Av,
                                                      const ushort* __restrict__ Wt,
                                                      const float* __restrict__ ss,
                                                      const float* __restrict__ dis,
                                                      ushort* __restrict__ hsc) {
  constexpr int BM = 128, BN = 128, BK = 32, K = 256;
  constexpr int LDP = BK + 8;  // 40 bf16 (80B) stride: conflict-free b128 frags
  __shared__ ushort As[BM * LDP];
  __shared__ ushort Bs[BN * LDP];
  const int tid = threadIdx.x;
  const int lane = tid & 63;
  const int wid = tid >> 6;
  const int wr = wid >> 1, wc = wid & 1;  // 2x2 wave grid
  constexpr int NB = D / BN;
  const int rb = (blockIdx.x / NB) * BM;
  const int cb = (blockIdx.x % NB) * BN;

  f32x4 acc[4][4];
#pragma unroll
  for (int m = 0; m < 4; ++m)
#pragma unroll
    for (int n = 0; n < 4; ++n) acc[m][n] = (f32x4)(0.f);

  for (int kt = 0; kt < K; kt += BK) {
    // stage A: 128 rows x 32 k. 512 tasks of 8 elems.
#pragma unroll
    for (int it = 0; it < 2; ++it) {
      int idx = tid + it * 256;
      int row = idx >> 2, kq = idx & 3;
      int gr = rb + row;
      if (gr >= N_NODES) gr = N_NODES - 1;
      float e[8];
      if constexpr (APPLY_BN) {
        const ushort* A = (const ushort*)Av;
        short8 v = *reinterpret_cast<const short8*>(&A[(size_t)gr * K + kt + kq * 8]);
#pragma unroll
        for (int q = 0; q < 8; ++q) {
          int k = kt + kq * 8 + q;
          e[q] = fmaxf(bf2f((ushort)v[q]) * ss[k] + ss[256 + k], 0.f);
        }
      } else {
        const float* A = (const float*)Av;
        const float4* src = reinterpret_cast<const float4*>(&A[(size_t)gr * K + kt + kq * 8]);
        float4 v0 = src[0], v1 = src[1];
        e[0] = v0.x; e[1] = v0.y; e[2] = v0.z; e[3] = v0.w;
        e[4] = v1.x; e[5] = v1.y; e[6] = v1.z; e[7] = v1.w;
      }
      short8 pk;
#pragma unroll
      for (int q = 0; q < 8; ++q) pk[q] = (short)f2bf(e[q]);
      *reinterpret_cast<short8*>(&As[row * LDP + kq * 8]) = pk;
    }
    // stage B from Wt (already bf16, k-contiguous)
#pragma unroll
    for (int it = 0; it < 2; ++it) {
      int idx = tid + it * 256;
      int n = idx >> 2, kq = idx & 3;
      short8 v = *reinterpret_cast<const short8*>(&Wt[(size_t)(cb + n) * K + kt + kq * 8]);
      *reinterpret_cast<short8*>(&Bs[n * LDP + kq * 8]) = v;
    }
    __syncthreads();

    const int rl = lane & 15;
    const int kb = (lane >> 4) * 8;
    short8 af[4], bfr[4];
#pragma unroll
    for (int f = 0; f < 4; ++f) {
      af[f] = *reinterpret_cast<short8*>(&As[(wr * 64 + f * 16 + rl) * LDP + kb]);
      bfr[f] = *reinterpret_cast<short8*>(&Bs[(wc * 64 + f * 16 + rl) * LDP + kb]);
    }
#pragma unroll
    for (int m = 0; m < 4; ++m)
#pragma unroll
      for (int n = 0; n < 4; ++n)
        acc[m][n] = __builtin_amdgcn_mfma_f32_16x16x32_bf16(af[m], bfr[n], acc[m][n], 0, 0, 0);
    __syncthreads();
  }

  // epilogue: *dis[row], cvt bf16, store chunk-major. C frag: col=lane&15, row=(lane>>4)*4+j.
  const int cl = lane & 15;
  const int rq = lane >> 4;
#pragma unroll
  for (int m = 0; m < 4; ++m) {
    int rbase = rb + wr * 64 + m * 16 + rq * 4;
#pragma unroll
    for (int j = 0; j < 4; ++j) {
      int row = rbase + j;
      if (row >= N_NODES) continue;
      float di = dis[row];
#pragma unroll
      for (int n = 0; n < 4; ++n) {
        int col = cb + wc * 64 + n * 16 + cl;
        size_t addr = ((size_t)(col / CW) * N_NODES + row) * CW + (col % CW);
        hsc[addr] = f2bf(acc[m][n][j] * di);
      }
    }
  }
}

// ---------------- chunked aggregation v2: out = dis*(self+sum_nbr) + b ------------
// hsc chunk-major [8][N][CW]; chunk = blockIdx&7 -> XCD affinity.
// Wave = (node, chunk). LPE=CW/4 lanes per edge (ushort4 = 8B each), EPW=64/LPE
// edges per load instruction; main loop 2x batched (16/32 edges in flight),
// guard-free; tail folds bounds into an fma weight (no divergent branch).
template <int CW, bool OUT_F32, int OUTD>
__global__ __launch_bounds__(256) void k_agg_chunk(const ushort* __restrict__ hsc,
                                                   const int* __restrict__ cs,
                                                   const int* __restrict__ rs,
                                                   const float* __restrict__ dis,
                                                   const float* __restrict__ bias,
                                                   void* __restrict__ outp) {
  constexpr int LPE = CW / 4;       // 8 for CW=32, 4 for CW=16
  constexpr int EPW = 64 / LPE;     // 8 or 16
  const int chunk = blockIdx.x & 7;
  const int node = (blockIdx.x >> 3) * 4 + (threadIdx.x >> 6);
  if (node >= N_NODES) return;
  const int lane = threadIdx.x & 63;
  const int k = lane & (LPE - 1);
  const int eslot = lane / LPE;
  const ushort* bc = hsc + (size_t)chunk * N_NODES * CW + k * 4;

  float a0 = 0.f, a1 = 0.f, a2 = 0.f, a3 = 0.f;
  if (eslot == 0) {
    ushort4 v = *reinterpret_cast<const ushort4*>(&bc[(size_t)node * CW]);
    a0 = bf2f(v.x);
    a1 = bf2f(v.y);
    a2 = bf2f(v.z);
    a3 = bf2f(v.w);
  }
  int s = rs[node], e = rs[node + 1];
  for (int b0 = s; b0 < e; b0 += 64) {
    int nav = min(64, e - b0);
    int idx = (b0 + lane < e) ? __builtin_nontemporal_load(&cs[b0 + lane]) : 0;
    int j = 0;
    // main: full groups, no bounds checks, two loads in flight
    for (; j + 2 * EPW <= nav; j += 2 * EPW) {
      int c0 = __shfl(idx, j + eslot);
      int c1 = __shfl(idx, j + EPW + eslot);
      ushort4 v0 = *reinterpret_cast<const ushort4*>(&bc[(size_t)((uint)c0 * CW)]);
      ushort4 v1 = *reinterpret_cast<const ushort4*>(&bc[(size_t)((uint)c1 * CW)]);
      a0 += bf2f(v0.x) + bf2f(v1.x);
      a1 += bf2f(v0.y) + bf2f(v1.y);
      a2 += bf2f(v0.z) + bf2f(v1.z);
      a3 += bf2f(v0.w) + bf2f(v1.w);
    }
    // tail: one guarded group (weight-folded, non-divergent)
    for (; j < nav; j += EPW) {
      int je = j + eslot;
      int c = __shfl(idx, je & 63);  // idx=0 beyond e -> row 0, weight 0
      float w = (je < nav) ? 1.f : 0.f;
      ushort4 v = *reinterpret_cast<const ushort4*>(&bc[(size_t)((uint)c * CW)]);
      a0 = fmaf(w, bf2f(v.x), a0);
      a1 = fmaf(w, bf2f(v.y), a1);
      a2 = fmaf(w, bf2f(v.z), a2);
      a3 = fmaf(w, bf2f(v.w), a3);
    }
  }
  // combine edge slots
#pragma unroll
  for (int off = LPE; off < 64; off <<= 1) {
    a0 += __shfl_xor(a0, off);
    a1 += __shfl_xor(a1, off);
    a2 += __shfl_xor(a2, off);
    a3 += __shfl_xor(a3, off);
  }
  if (eslot == 0) {
    float di = dis[node];
    float4 b = *reinterpret_cast<const float4*>(&bias[chunk * CW + k * 4]);
    float o0 = a0 * di + b.x, o1 = a1 * di + b.y;
    float o2 = a2 * di + b.z, o3 = a3 * di + b.w;
    if constexpr (OUT_F32) {
      float* out = (float*)outp;
      float4 o = {o0, o1, o2, o3};
      *reinterpret_cast<float4*>(&out[(size_t)node * OUTD + chunk * CW + k * 4]) = o;
    } else {
      ushort* out = (ushort*)outp;
      ushort4 o;
      o.x = f2bf(o0);
      o.y = f2bf(o1);
      o.z = f2bf(o2);
      o.w = f2bf(o3);
      *reinterpret_cast<ushort4*>(&out[(size_t)node * OUTD + chunk * CW + k * 4]) = o;
    }
  }
}

// ---------------- log_softmax over D=128 f32 logits (wave per node) ----------------
__global__ __launch_bounds__(256) void k_lsm(const float* __restrict__ pre2,
                                             float* __restrict__ out) {
  int node = (blockIdx.x * 256 + threadIdx.x) >> 6;
  if (node >= N_NODES) return;
  int lane = threadIdx.x & 63;
  float2 v = *reinterpret_cast<const float2*>(&pre2[(size_t)node * 128 + lane * 2]);
  float m = fmaxf(v.x, v.y);
#pragma unroll
  for (int o = 1; o < 64; o <<= 1) m = fmaxf(m, __shfl_xor(m, o));
  float sum = __expf(v.x - m) + __expf(v.y - m);
#pragma unroll
  for (int o = 1; o < 64; o <<= 1) sum += __shfl_xor(sum, o);
  float ls = m + logf(sum);
  float2 o2 = {v.x - ls, v.y - ls};
  *reinterpret_cast<float2*>(&out[(size_t)node * 128 + lane * 2]) = o2;
}

// ---------------- batchnorm stats: three-phase, atomic-free ----------------
__global__ __launch_bounds__(256) void k_bnstatsA(const ushort* __restrict__ pre,
                                                  float* __restrict__ partial) {
  int t = threadIdx.x;
  int rsub = t >> 7;
  int cp = (t & 127) * 2;
  float s0 = 0.f, s1 = 0.f, q0 = 0.f, q1 = 0.f;
  for (int r = blockIdx.x * 2 + rsub; r < N_NODES; r += BNA_BLOCKS * 2) {
    ushort2 v = *reinterpret_cast<const ushort2*>(&pre[(size_t)r * 256 + cp]);
    float f0 = bf2f(v.x), f1 = bf2f(v.y);
    s0 += f0;
    q0 += f0 * f0;
    s1 += f1;
    q1 += f1 * f1;
  }
  __shared__ float lsum[256], lsq[256];
  if (rsub) {
    lsum[cp] = s0;
    lsum[cp + 1] = s1;
    lsq[cp] = q0;
    lsq[cp + 1] = q1;
  }
  __syncthreads();
  if (!rsub) {
    float* p = &partial[(size_t)blockIdx.x * 512];
    p[cp] = s0 + lsum[cp];
    p[cp + 1] = s1 + lsum[cp + 1];
    p[256 + cp] = q0 + lsq[cp];
    p[256 + cp + 1] = q1 + lsq[cp + 1];
  }
}

__global__ __launch_bounds__(512) void k_bnstatsB(const float* __restrict__ partial,
                                                  float* __restrict__ p2) {
  int t = threadIdx.x, b = blockIdx.x;
  float a = 0.f;
#pragma unroll 8
  for (int r = 0; r < BNA_BLOCKS / 8; ++r)
    a += partial[(size_t)(b * (BNA_BLOCKS / 8) + r) * 512 + t];
  p2[(size_t)b * 512 + t] = a;
}

__global__ void k_bnfinal(const float* __restrict__ p2, const float* __restrict__ gamma,
                          const float* __restrict__ beta, float* __restrict__ ss) {
  int t = threadIdx.x;
  float sum = 0.f, sq = 0.f;
#pragma unroll
  for (int b = 0; b < 8; ++b) {
    sum += p2[(size_t)b * 512 + t];
    sq += p2[(size_t)b * 512 + 256 + t];
  }
  float mu = sum * (1.f / N_NODES);
  float var = sq * (1.f / N_NODES) - mu * mu;
  float sc = gamma[t] * rsqrtf(var + BN_EPS);
  ss[t] = sc;
  ss[256 + t] = beta[t] - mu * sc;
}

// ---------------- launcher ----------------
extern "C" void kernel_launch(void* const* d_in, const int* in_sizes, int n_in,
                              void* d_out, int out_size, void* d_ws, size_t ws_size,
                              hipStream_t stream) {
  const float* x = (const float*)d_in[0];
  const int* erow = (const int*)d_in[1];
  const int* ecol = erow + N_EDGES;
  const float* W0 = (const float*)d_in[2];
  const float* b0 = (const float*)d_in[3];
  const float* W1 = (const float*)d_in[4];
  const float* b1 = (const float*)d_in[5];
  const float* W2 = (const float*)d_in[6];
  const float* b2 = (const float*)d_in[7];
  const float* g0 = (const float*)d_in[8];
  const float* be0 = (const float*)d_in[9];
  const float* g1 = (const float*)d_in[10];
  const float* be1 = (const float*)d_in[11];
  float* out = (float*)d_out;

  char* ws = (char*)d_ws;
  size_t off = 0;
  auto take = [&](size_t bytes) {
    char* p = ws + off;
    off = (off + bytes + 255) & ~(size_t)255;
    return p;
  };
  int* deg = (int*)take(N_NODES * 4);
  int* fill = (int*)take(N_NODES * 4);
  size_t zero_bytes = off;  // deg+fill must start at 0 each call
  float* bnpart = (float*)take((size_t)BNA_BLOCKS * 512 * 4);
  float* bnpart2 = (float*)take(8 * 512 * 4);
  float* dis = (float*)take(N_NODES * 4);
  int* row_start = (int*)take((N_NODES + 1) * 4);
  int* bsum = (int*)take(256 * 4);
  int* boff = (int*)take(256 * 4);
  float* ss0 = (float*)take(512 * 4);
  float* ss1 = (float*)take(512 * 4);
  ushort* Wt0 = (ushort*)take(256 * 256 * 2);
  ushort* Wt1 = (ushort*)take(256 * 256 * 2);
  ushort* Wt2 = (ushort*)take(256 * 128 * 2);
  int* col_sorted = (int*)take((size_t)N_EDGES * 4);
  ushort* hsc = (ushort*)take((size_t)N_NODES * 256 * 2);   // chunk-major
  ushort* pre = (ushort*)take((size_t)N_NODES * 256 * 2);   // row-major bf16
  float* pre2 = (float*)take((size_t)N_NODES * 128 * 4);    // f32 logits
  if (off > ws_size) return;

  hipMemsetAsync(d_ws, 0, zero_bytes, stream);

  k_deg<<<1024, 256, 0, stream>>>(erow, deg);
  k_disqrt<<<(N_NODES + 255) / 256, 256, 0, stream>>>(deg, dis);
  int nb = (N_NODES + 255) / 256;  // 196
  k_scan_part<<<nb, 256, 0, stream>>>(deg, bsum);
  k_scan_top<<<1, 256, 0, stream>>>(bsum, boff, nb);
  k_scan_final<<<nb, 256, 0, stream>>>(deg, boff, row_start);
  k_scatter<<<1024, 256, 0, stream>>>(erow, ecol, row_start, fill, col_sorted);

  k_wt<<<(256 * 256 + 255) / 256, 256, 0, stream>>>(W0, Wt0, 256, 256);
  k_wt<<<(256 * 256 + 255) / 256, 256, 0, stream>>>(W1, Wt1, 256, 256);
  k_wt<<<(256 * 128 + 255) / 256, 256, 0, stream>>>(W2, Wt2, 256, 128);

  int mblocks = (N_NODES + 127) / 128;        // 391
  int aggc_grid = (N_NODES / 4) * 8;          // 100000
  int lsm_grid = (N_NODES * 64 + 255) / 256;  // 12500
  // layer 0
  k_gemm_bf16<256, 32, false><<<mblocks * 2, 256, 0, stream>>>(x, Wt0, nullptr, dis, hsc);
  k_agg_chunk<32, false, 256><<<aggc_grid, 256, 0, stream>>>(hsc, col_sorted, row_start, dis, b0, pre);
  k_bnstatsA<<<BNA_BLOCKS, 256, 0, stream>>>(pre, bnpart);
  k_bnstatsB<<<8, 512, 0, stream>>>(bnpart, bnpart2);
  k_bnfinal<<<1, 256, 0, stream>>>(bnpart2, g0, be0, ss0);
  // layer 1
  k_gemm_bf16<256, 32, true><<<mblocks * 2, 256, 0, stream>>>(pre, Wt1, ss0, dis, hsc);
  k_agg_chunk<32, false, 256><<<aggc_grid, 256, 0, stream>>>(hsc, col_sorted, row_start, dis, b1, pre);
  k_bnstatsA<<<BNA_BLOCKS, 256, 0, stream>>>(pre, bnpart);
  k_bnstatsB<<<8, 512, 0, stream>>>(bnpart, bnpart2);
  k_bnfinal<<<1, 256, 0, stream>>>(bnpart2, g1, be1, ss1);
  // layer 2: GEMM -> chunked agg (f32 logits) -> log_softmax
  k_gemm_bf16<128, 16, true><<<mblocks, 256, 0, stream>>>(pre, Wt2, ss1, dis, hsc);
  k_agg_chunk<16, true, 128><<<aggc_grid, 256, 0, stream>>>(hsc, col_sorted, row_start, dis, b2, pre2);
  k_lsm<<<lsm_grid, 256, 0, stream>>>(pre2, out);
}

// Round 9
// 550.030 us; speedup vs baseline: 1.2406x; 1.2333x over previous
//
#include <hip/hip_runtime.h>

constexpr int N_NODES = 50000;
constexpr int N_EDGES = 800000;
constexpr float BN_EPS = 1e-5f;
constexpr int BNA_BLOCKS = 256;

typedef __attribute__((ext_vector_type(8))) short short8;
typedef __attribute__((ext_vector_type(4))) float f32x4;

__device__ __forceinline__ float bf2f(ushort u) {
  union { uint i; float f; } v;
  v.i = ((uint)u) << 16;
  return v.f;
}
__device__ __forceinline__ ushort f2bf(float f) {
  union { float f; uint i; } v;
  v.f = f;
  uint r = v.i + 0x7fff + ((v.i >> 16) & 1);  // RNE
  return (ushort)(r >> 16);
}

// ---------------- degree / normalization ----------------
__global__ void k_deg(const int* __restrict__ row, int* __restrict__ deg) {
  int i = blockIdx.x * blockDim.x + threadIdx.x;
  int stride = gridDim.x * blockDim.x;
  for (; i < N_EDGES; i += stride) atomicAdd(&deg[row[i]], 1);
}

__global__ void k_disqrt(const int* __restrict__ deg, float* __restrict__ dis) {
  int i = blockIdx.x * blockDim.x + threadIdx.x;
  if (i < N_NODES) dis[i] = rsqrtf((float)(deg[i] + 1));
}

// ---------------- CSR build: 3-phase scan + scatter ----------------
__global__ void k_scan_part(const int* __restrict__ deg, int* __restrict__ bsum) {
  __shared__ int s[256];
  int t = threadIdx.x, i = blockIdx.x * 256 + t;
  s[t] = (i < N_NODES) ? deg[i] : 0;
  __syncthreads();
  for (int off = 128; off > 0; off >>= 1) {
    if (t < off) s[t] += s[t + off];
    __syncthreads();
  }
  if (t == 0) bsum[blockIdx.x] = s[0];
}

__global__ void k_scan_top(const int* __restrict__ bsum, int* __restrict__ boff, int nb) {
  __shared__ int s[256];
  int t = threadIdx.x;
  int v = (t < nb) ? bsum[t] : 0;
  s[t] = v;
  __syncthreads();
  for (int off = 1; off < 256; off <<= 1) {
    int x = (t >= off) ? s[t - off] : 0;
    __syncthreads();
    s[t] += x;
    __syncthreads();
  }
  if (t < nb) boff[t] = s[t] - v;  // exclusive
}

__global__ void k_scan_final(const int* __restrict__ deg, const int* __restrict__ boff,
                             int* __restrict__ row_start) {
  __shared__ int s[256];
  int t = threadIdx.x, i = blockIdx.x * 256 + t;
  int v = (i < N_NODES) ? deg[i] : 0;
  s[t] = v;
  __syncthreads();
  for (int off = 1; off < 256; off <<= 1) {
    int x = (t >= off) ? s[t - off] : 0;
    __syncthreads();
    s[t] += x;
    __syncthreads();
  }
  if (i < N_NODES) row_start[i] = boff[blockIdx.x] + s[t] - v;
  if (i == 0) row_start[N_NODES] = N_EDGES;
}

__global__ void k_scatter(const int* __restrict__ row, const int* __restrict__ col,
                          const int* __restrict__ row_start, int* __restrict__ fill,
                          int* __restrict__ col_sorted) {
  int i = blockIdx.x * blockDim.x + threadIdx.x;
  int stride = gridDim.x * blockDim.x;
  for (; i < N_EDGES; i += stride) {
    int r = row[i];
    int pos = row_start[r] + atomicAdd(&fill[r], 1);
    col_sorted[pos] = col[i];
  }
}

// ---------------- counting sort of nodes by degree (256 bins) ----------------
__global__ void k_hist(const int* __restrict__ deg, int* __restrict__ hist) {
  __shared__ int h[256];
  int t = threadIdx.x;
  h[t] = 0;
  __syncthreads();
  for (int i = blockIdx.x * 256 + t; i < N_NODES; i += gridDim.x * 256)
    atomicAdd(&h[min(deg[i], 255)], 1);
  __syncthreads();
  if (h[t]) atomicAdd(&hist[t], h[t]);
}

__global__ void k_hist_scan(const int* __restrict__ hist, int* __restrict__ binoff) {
  __shared__ int s[256];
  int t = threadIdx.x;
  int v = hist[t];
  s[t] = v;
  __syncthreads();
  for (int off = 1; off < 256; off <<= 1) {
    int x = (t >= off) ? s[t - off] : 0;
    __syncthreads();
    s[t] += x;
    __syncthreads();
  }
  binoff[t] = s[t] - v;  // exclusive
}

__global__ void k_sortscatter(const int* __restrict__ deg, const int* __restrict__ binoff,
                              int* __restrict__ binfill, int* __restrict__ nodemap) {
  int i = blockIdx.x * 256 + threadIdx.x;
  if (i >= N_NODES) return;
  int b = min(deg[i], 255);
  int pos = binoff[b] + atomicAdd(&binfill[b], 1);
  nodemap[pos] = i;
}

// ---------------- W transpose to bf16: Wt[n][k] = bf16(W[k][n]) ----------------
__global__ void k_wt(const float* __restrict__ W, ushort* __restrict__ Wt, int K, int N) {
  int idx = blockIdx.x * 256 + threadIdx.x;
  if (idx >= K * N) return;
  int n = idx / K, k = idx % K;
  Wt[idx] = f2bf(W[(size_t)k * N + n]);
}

// ---------------- bf16 MFMA GEMM: hsc = bf16( f(A) @ W * d_isqrt ), chunk-major ----
template <int D, int CW, bool APPLY_BN>
__global__ __launch_bounds__(256, 3) void k_gemm_bf16(const void* __restrict__ Av,
                                                      const ushort* __restrict__ Wt,
                                                      const float* __restrict__ ss,
                                                      const float* __restrict__ dis,
                                                      ushort* __restrict__ hsc) {
  constexpr int BM = 128, BN = 128, BK = 32, K = 256;
  constexpr int LDP = BK + 8;  // 40 bf16 (80B) stride: conflict-free b128 frags
  __shared__ ushort As[BM * LDP];
  __shared__ ushort Bs[BN * LDP];
  const int tid = threadIdx.x;
  const int lane = tid & 63;
  const int wid = tid >> 6;
  const int wr = wid >> 1, wc = wid & 1;  // 2x2 wave grid
  constexpr int NB = D / BN;
  const int rb = (blockIdx.x / NB) * BM;
  const int cb = (blockIdx.x % NB) * BN;

  f32x4 acc[4][4];
#pragma unroll
  for (int m = 0; m < 4; ++m)
#pragma unroll
    for (int n = 0; n < 4; ++n) acc[m][n] = (f32x4)(0.f);

  for (int kt = 0; kt < K; kt += BK) {
#pragma unroll
    for (int it = 0; it < 2; ++it) {
      int idx = tid + it * 256;
      int row = idx >> 2, kq = idx & 3;
      int gr = rb + row;
      if (gr >= N_NODES) gr = N_NODES - 1;
      float e[8];
      if constexpr (APPLY_BN) {
        const ushort* A = (const ushort*)Av;
        short8 v = *reinterpret_cast<const short8*>(&A[(size_t)gr * K + kt + kq * 8]);
#pragma unroll
        for (int q = 0; q < 8; ++q) {
          int k = kt + kq * 8 + q;
          e[q] = fmaxf(bf2f((ushort)v[q]) * ss[k] + ss[256 + k], 0.f);
        }
      } else {
        const float* A = (const float*)Av;
        const float4* src = reinterpret_cast<const float4*>(&A[(size_t)gr * K + kt + kq * 8]);
        float4 v0 = src[0], v1 = src[1];
        e[0] = v0.x; e[1] = v0.y; e[2] = v0.z; e[3] = v0.w;
        e[4] = v1.x; e[5] = v1.y; e[6] = v1.z; e[7] = v1.w;
      }
      short8 pk;
#pragma unroll
      for (int q = 0; q < 8; ++q) pk[q] = (short)f2bf(e[q]);
      *reinterpret_cast<short8*>(&As[row * LDP + kq * 8]) = pk;
    }
#pragma unroll
    for (int it = 0; it < 2; ++it) {
      int idx = tid + it * 256;
      int n = idx >> 2, kq = idx & 3;
      short8 v = *reinterpret_cast<const short8*>(&Wt[(size_t)(cb + n) * K + kt + kq * 8]);
      *reinterpret_cast<short8*>(&Bs[n * LDP + kq * 8]) = v;
    }
    __syncthreads();

    const int rl = lane & 15;
    const int kb = (lane >> 4) * 8;
    short8 af[4], bfr[4];
#pragma unroll
    for (int f = 0; f < 4; ++f) {
      af[f] = *reinterpret_cast<short8*>(&As[(wr * 64 + f * 16 + rl) * LDP + kb]);
      bfr[f] = *reinterpret_cast<short8*>(&Bs[(wc * 64 + f * 16 + rl) * LDP + kb]);
    }
#pragma unroll
    for (int m = 0; m < 4; ++m)
#pragma unroll
      for (int n = 0; n < 4; ++n)
        acc[m][n] = __builtin_amdgcn_mfma_f32_16x16x32_bf16(af[m], bfr[n], acc[m][n], 0, 0, 0);
    __syncthreads();
  }

  const int cl = lane & 15;
  const int rq = lane >> 4;
#pragma unroll
  for (int m = 0; m < 4; ++m) {
    int rbase = rb + wr * 64 + m * 16 + rq * 4;
#pragma unroll
    for (int j = 0; j < 4; ++j) {
      int row = rbase + j;
      if (row >= N_NODES) continue;
      float di = dis[row];
#pragma unroll
      for (int n = 0; n < 4; ++n) {
        int col = cb + wc * 64 + n * 16 + cl;
        size_t addr = ((size_t)(col / CW) * N_NODES + row) * CW + (col % CW);
        hsc[addr] = f2bf(acc[m][n][j] * di);
      }
    }
  }
}

// ---------------- chunked agg v3: lane owns (node, 4 cols); no reduction ----------
// hsc chunk-major [8][N][CW]; chunk = blockIdx&7 -> XCD affinity.
// Wave = NG nodes x LPG lanes (NG=64/LPG, LPG=CW/4). Nodes taken in degree-sorted
// order (nodemap) so per-wave loop divergence ~ 0. Lane k of group g accumulates
// node's cols [k*4, k*4+4) over all its edges; index batch preloaded per LPG steps,
// shfl-broadcast within group; LPG independent gathers in flight.
template <int CW, bool OUT_F32, int OUTD>
__global__ __launch_bounds__(256) void k_agg_sorted(const ushort* __restrict__ hsc,
                                                    const int* __restrict__ cs,
                                                    const int* __restrict__ rs,
                                                    const int* __restrict__ nodemap,
                                                    const float* __restrict__ dis,
                                                    const float* __restrict__ bias,
                                                    void* __restrict__ outp) {
  constexpr int LPG = CW / 4;   // lanes per node group: 8 (CW=32) / 4 (CW=16)
  constexpr int NG = 64 / LPG;  // nodes per wave: 8 / 16
  const int chunk = blockIdx.x & 7;
  const int wave = threadIdx.x >> 6;
  const int lane = threadIdx.x & 63;
  const int g = lane / LPG;
  const int k = lane & (LPG - 1);
  const int spos = (blockIdx.x >> 3) * (4 * NG) + wave * NG + g;
  const bool alive = spos < N_NODES;
  const int node = alive ? nodemap[spos] : 0;
  const int s = rs[node];
  const int deg = alive ? (rs[node + 1] - s) : 0;
  const ushort* bc = hsc + (size_t)chunk * N_NODES * CW + k * 4;

  // self contribution
  ushort4 sv = *reinterpret_cast<const ushort4*>(&bc[(size_t)node * CW]);
  float a0 = bf2f(sv.x), a1 = bf2f(sv.y), a2 = bf2f(sv.z), a3 = bf2f(sv.w);

  int jb = 0;
  for (; jb + LPG <= deg; jb += LPG) {
    int idxk = cs[s + jb + k];  // lane k holds index for step k
    ushort4 v[LPG];
#pragma unroll
    for (int st = 0; st < LPG; ++st) {
      int c = __shfl(idxk, g * LPG + st);
      v[st] = *reinterpret_cast<const ushort4*>(&bc[(size_t)((uint)c * CW)]);
    }
#pragma unroll
    for (int st = 0; st < LPG; ++st) {
      a0 += bf2f(v[st].x);
      a1 += bf2f(v[st].y);
      a2 += bf2f(v[st].z);
      a3 += bf2f(v[st].w);
    }
  }
  if (jb < deg) {  // tail batch, weight-folded
    int idxk = (jb + k < deg) ? cs[s + jb + k] : 0;
    ushort4 v[LPG];
#pragma unroll
    for (int st = 0; st < LPG; ++st) {
      int c = __shfl(idxk, g * LPG + st);
      v[st] = *reinterpret_cast<const ushort4*>(&bc[(size_t)((uint)c * CW)]);
    }
#pragma unroll
    for (int st = 0; st < LPG; ++st) {
      float w = (jb + st < deg) ? 1.f : 0.f;
      a0 = fmaf(w, bf2f(v[st].x), a0);
      a1 = fmaf(w, bf2f(v[st].y), a1);
      a2 = fmaf(w, bf2f(v[st].z), a2);
      a3 = fmaf(w, bf2f(v[st].w), a3);
    }
  }

  if (alive) {
    float di = dis[node];
    float4 b = *reinterpret_cast<const float4*>(&bias[chunk * CW + k * 4]);
    float o0 = a0 * di + b.x, o1 = a1 * di + b.y;
    float o2 = a2 * di + b.z, o3 = a3 * di + b.w;
    if constexpr (OUT_F32) {
      float* out = (float*)outp;
      float4 o = {o0, o1, o2, o3};
      *reinterpret_cast<float4*>(&out[(size_t)node * OUTD + chunk * CW + k * 4]) = o;
    } else {
      ushort* out = (ushort*)outp;
      ushort4 o;
      o.x = f2bf(o0);
      o.y = f2bf(o1);
      o.z = f2bf(o2);
      o.w = f2bf(o3);
      *reinterpret_cast<ushort4*>(&out[(size_t)node * OUTD + chunk * CW + k * 4]) = o;
    }
  }
}

// ---------------- log_softmax over D=128 f32 logits (wave per node) ----------------
__global__ __launch_bounds__(256) void k_lsm(const float* __restrict__ pre2,
                                             float* __restrict__ out) {
  int node = (blockIdx.x * 256 + threadIdx.x) >> 6;
  if (node >= N_NODES) return;
  int lane = threadIdx.x & 63;
  float2 v = *reinterpret_cast<const float2*>(&pre2[(size_t)node * 128 + lane * 2]);
  float m = fmaxf(v.x, v.y);
#pragma unroll
  for (int o = 1; o < 64; o <<= 1) m = fmaxf(m, __shfl_xor(m, o));
  float sum = __expf(v.x - m) + __expf(v.y - m);
#pragma unroll
  for (int o = 1; o < 64; o <<= 1) sum += __shfl_xor(sum, o);
  float ls = m + logf(sum);
  float2 o2 = {v.x - ls, v.y - ls};
  *reinterpret_cast<float2*>(&out[(size_t)node * 128 + lane * 2]) = o2;
}

// ---------------- batchnorm stats: three-phase, atomic-free ----------------
__global__ __launch_bounds__(256) void k_bnstatsA(const ushort* __restrict__ pre,
                                                  float* __restrict__ partial) {
  int t = threadIdx.x;
  int rsub = t >> 7;
  int cp = (t & 127) * 2;
  float s0 = 0.f, s1 = 0.f, q0 = 0.f, q1 = 0.f;
  for (int r = blockIdx.x * 2 + rsub; r < N_NODES; r += BNA_BLOCKS * 2) {
    ushort2 v = *reinterpret_cast<const ushort2*>(&pre[(size_t)r * 256 + cp]);
    float f0 = bf2f(v.x), f1 = bf2f(v.y);
    s0 += f0;
    q0 += f0 * f0;
    s1 += f1;
    q1 += f1 * f1;
  }
  __shared__ float lsum[256], lsq[256];
  if (rsub) {
    lsum[cp] = s0;
    lsum[cp + 1] = s1;
    lsq[cp] = q0;
    lsq[cp + 1] = q1;
  }
  __syncthreads();
  if (!rsub) {
    float* p = &partial[(size_t)blockIdx.x * 512];
    p[cp] = s0 + lsum[cp];
    p[cp + 1] = s1 + lsum[cp + 1];
    p[256 + cp] = q0 + lsq[cp];
    p[256 + cp + 1] = q1 + lsq[cp + 1];
  }
}

__global__ __launch_bounds__(512) void k_bnstatsB(const float* __restrict__ partial,
                                                  float* __restrict__ p2) {
  int t = threadIdx.x, b = blockIdx.x;
  float a = 0.f;
#pragma unroll 8
  for (int r = 0; r < BNA_BLOCKS / 8; ++r)
    a += partial[(size_t)(b * (BNA_BLOCKS / 8) + r) * 512 + t];
  p2[(size_t)b * 512 + t] = a;
}

__global__ void k_bnfinal(const float* __restrict__ p2, const float* __restrict__ gamma,
                          const float* __restrict__ beta, float* __restrict__ ss) {
  int t = threadIdx.x;
  float sum = 0.f, sq = 0.f;
#pragma unroll
  for (int b = 0; b < 8; ++b) {
    sum += p2[(size_t)b * 512 + t];
    sq += p2[(size_t)b * 512 + 256 + t];
  }
  float mu = sum * (1.f / N_NODES);
  float var = sq * (1.f / N_NODES) - mu * mu;
  float sc = gamma[t] * rsqrtf(var + BN_EPS);
  ss[t] = sc;
  ss[256 + t] = beta[t] - mu * sc;
}

// ---------------- launcher ----------------
extern "C" void kernel_launch(void* const* d_in, const int* in_sizes, int n_in,
                              void* d_out, int out_size, void* d_ws, size_t ws_size,
                              hipStream_t stream) {
  const float* x = (const float*)d_in[0];
  const int* erow = (const int*)d_in[1];
  const int* ecol = erow + N_EDGES;
  const float* W0 = (const float*)d_in[2];
  const float* b0 = (const float*)d_in[3];
  const float* W1 = (const float*)d_in[4];
  const float* b1 = (const float*)d_in[5];
  const float* W2 = (const float*)d_in[6];
  const float* b2 = (const float*)d_in[7];
  const float* g0 = (const float*)d_in[8];
  const float* be0 = (const float*)d_in[9];
  const float* g1 = (const float*)d_in[10];
  const float* be1 = (const float*)d_in[11];
  float* out = (float*)d_out;

  char* ws = (char*)d_ws;
  size_t off = 0;
  auto take = [&](size_t bytes) {
    char* p = ws + off;
    off = (off + bytes + 255) & ~(size_t)255;
    return p;
  };
  int* deg = (int*)take(N_NODES * 4);
  int* fill = (int*)take(N_NODES * 4);
  int* hist = (int*)take(256 * 4);
  int* binfill = (int*)take(256 * 4);
  size_t zero_bytes = off;  // deg/fill/hist/binfill must start at 0 each call
  int* binoff = (int*)take(256 * 4);
  int* nodemap = (int*)take(N_NODES * 4);
  float* bnpart = (float*)take((size_t)BNA_BLOCKS * 512 * 4);
  float* bnpart2 = (float*)take(8 * 512 * 4);
  float* dis = (float*)take(N_NODES * 4);
  int* row_start = (int*)take((N_NODES + 1) * 4);
  int* bsum = (int*)take(256 * 4);
  int* boff = (int*)take(256 * 4);
  float* ss0 = (float*)take(512 * 4);
  float* ss1 = (float*)take(512 * 4);
  ushort* Wt0 = (ushort*)take(256 * 256 * 2);
  ushort* Wt1 = (ushort*)take(256 * 256 * 2);
  ushort* Wt2 = (ushort*)take(256 * 128 * 2);
  int* col_sorted = (int*)take((size_t)N_EDGES * 4);
  ushort* hsc = (ushort*)take((size_t)N_NODES * 256 * 2);   // chunk-major
  ushort* pre = (ushort*)take((size_t)N_NODES * 256 * 2);   // row-major bf16
  float* pre2 = (float*)take((size_t)N_NODES * 128 * 4);    // f32 logits
  if (off > ws_size) return;

  hipMemsetAsync(d_ws, 0, zero_bytes, stream);

  k_deg<<<1024, 256, 0, stream>>>(erow, deg);
  k_disqrt<<<(N_NODES + 255) / 256, 256, 0, stream>>>(deg, dis);
  int nb = (N_NODES + 255) / 256;  // 196
  k_scan_part<<<nb, 256, 0, stream>>>(deg, bsum);
  k_scan_top<<<1, 256, 0, stream>>>(bsum, boff, nb);
  k_scan_final<<<nb, 256, 0, stream>>>(deg, boff, row_start);
  k_scatter<<<1024, 256, 0, stream>>>(erow, ecol, row_start, fill, col_sorted);

  // degree sort
  k_hist<<<128, 256, 0, stream>>>(deg, hist);
  k_hist_scan<<<1, 256, 0, stream>>>(hist, binoff);
  k_sortscatter<<<nb, 256, 0, stream>>>(deg, binoff, binfill, nodemap);

  k_wt<<<(256 * 256 + 255) / 256, 256, 0, stream>>>(W0, Wt0, 256, 256);
  k_wt<<<(256 * 256 + 255) / 256, 256, 0, stream>>>(W1, Wt1, 256, 256);
  k_wt<<<(256 * 128 + 255) / 256, 256, 0, stream>>>(W2, Wt2, 256, 128);

  int mblocks = (N_NODES + 127) / 128;                 // 391
  int agg32_grid = ((N_NODES + 31) / 32) * 8;          // 12504
  int agg16_grid = ((N_NODES + 63) / 64) * 8;          // 6256
  int lsm_grid = (N_NODES * 64 + 255) / 256;           // 12500
  // layer 0
  k_gemm_bf16<256, 32, false><<<mblocks * 2, 256, 0, stream>>>(x, Wt0, nullptr, dis, hsc);
  k_agg_sorted<32, false, 256><<<agg32_grid, 256, 0, stream>>>(hsc, col_sorted, row_start, nodemap, dis, b0, pre);
  k_bnstatsA<<<BNA_BLOCKS, 256, 0, stream>>>(pre, bnpart);
  k_bnstatsB<<<8, 512, 0, stream>>>(bnpart, bnpart2);
  k_bnfinal<<<1, 256, 0, stream>>>(bnpart2, g0, be0, ss0);
  // layer 1
  k_gemm_bf16<256, 32, true><<<mblocks * 2, 256, 0, stream>>>(pre, Wt1, ss0, dis, hsc);
  k_agg_sorted<32, false, 256><<<agg32_grid, 256, 0, stream>>>(hsc, col_sorted, row_start, nodemap, dis, b1, pre);
  k_bnstatsA<<<BNA_BLOCKS, 256, 0, stream>>>(pre, bnpart);
  k_bnstatsB<<<8, 512, 0, stream>>>(bnpart, bnpart2);
  k_bnfinal<<<1, 256, 0, stream>>>(bnpart2, g1, be1, ss1);
  // layer 2: GEMM -> chunked agg (f32 logits) -> log_softmax
  k_gemm_bf16<128, 16, true><<<mblocks, 256, 0, stream>>>(pre, Wt2, ss1, dis, hsc);
  k_agg_sorted<16, true, 128><<<agg16_grid, 256, 0, stream>>>(hsc, col_sorted, row_start, nodemap, dis, b2, pre2);
  k_lsm<<<lsm_grid, 256, 0, stream>>>(pre2, out);
}

// Round 10
// 462.096 us; speedup vs baseline: 1.4767x; 1.1903x over previous
//
#include <hip/hip_runtime.h>

constexpr int N_NODES = 50000;
constexpr int N_EDGES = 800000;
constexpr float BN_EPS = 1e-5f;
constexpr int BNA_BLOCKS = 256;

typedef __attribute__((ext_vector_type(8))) short short8;
typedef __attribute__((ext_vector_type(4))) float f32x4;

__device__ __forceinline__ float bf2f(ushort u) {
  union { uint i; float f; } v;
  v.i = ((uint)u) << 16;
  return v.f;
}
__device__ __forceinline__ ushort f2bf(float f) {
  union { float f; uint i; } v;
  v.f = f;
  uint r = v.i + 0x7fff + ((v.i >> 16) & 1);  // RNE
  return (ushort)(r >> 16);
}

// ---------------- degree / normalization ----------------
__global__ void k_deg(const int* __restrict__ row, int* __restrict__ deg) {
  int i = blockIdx.x * blockDim.x + threadIdx.x;
  int stride = gridDim.x * blockDim.x;
  for (; i < N_EDGES; i += stride) atomicAdd(&deg[row[i]], 1);
}

__global__ void k_disqrt(const int* __restrict__ deg, float* __restrict__ dis) {
  int i = blockIdx.x * blockDim.x + threadIdx.x;
  if (i < N_NODES) dis[i] = rsqrtf((float)(deg[i] + 1));
}

// ---------------- CSR build: 3-phase scan + scatter ----------------
__global__ void k_scan_part(const int* __restrict__ deg, int* __restrict__ bsum) {
  __shared__ int s[256];
  int t = threadIdx.x, i = blockIdx.x * 256 + t;
  s[t] = (i < N_NODES) ? deg[i] : 0;
  __syncthreads();
  for (int off = 128; off > 0; off >>= 1) {
    if (t < off) s[t] += s[t + off];
    __syncthreads();
  }
  if (t == 0) bsum[blockIdx.x] = s[0];
}

__global__ void k_scan_top(const int* __restrict__ bsum, int* __restrict__ boff, int nb) {
  __shared__ int s[256];
  int t = threadIdx.x;
  int v = (t < nb) ? bsum[t] : 0;
  s[t] = v;
  __syncthreads();
  for (int off = 1; off < 256; off <<= 1) {
    int x = (t >= off) ? s[t - off] : 0;
    __syncthreads();
    s[t] += x;
    __syncthreads();
  }
  if (t < nb) boff[t] = s[t] - v;  // exclusive
}

__global__ void k_scan_final(const int* __restrict__ deg, const int* __restrict__ boff,
                             int* __restrict__ row_start) {
  __shared__ int s[256];
  int t = threadIdx.x, i = blockIdx.x * 256 + t;
  int v = (i < N_NODES) ? deg[i] : 0;
  s[t] = v;
  __syncthreads();
  for (int off = 1; off < 256; off <<= 1) {
    int x = (t >= off) ? s[t - off] : 0;
    __syncthreads();
    s[t] += x;
    __syncthreads();
  }
  if (i < N_NODES) row_start[i] = boff[blockIdx.x] + s[t] - v;
  if (i == 0) row_start[N_NODES] = N_EDGES;
}

__global__ void k_scatter(const int* __restrict__ row, const int* __restrict__ col,
                          const int* __restrict__ row_start, int* __restrict__ fill,
                          int* __restrict__ col_sorted) {
  int i = blockIdx.x * blockDim.x + threadIdx.x;
  int stride = gridDim.x * blockDim.x;
  for (; i < N_EDGES; i += stride) {
    int r = row[i];
    int pos = row_start[r] + atomicAdd(&fill[r], 1);
    col_sorted[pos] = col[i];
  }
}

// ---------------- degree sort: stable two-level counting sort, no global atomics ----
// bh[block][256]: per-block histogram
__global__ void k_blockhist(const int* __restrict__ deg, int* __restrict__ bh) {
  __shared__ int h[256];
  int t = threadIdx.x;
  h[t] = 0;
  __syncthreads();
  int i = blockIdx.x * 256 + t;
  if (i < N_NODES) atomicAdd(&h[min(deg[i], 255)], 1);
  __syncthreads();
  bh[blockIdx.x * 256 + t] = h[t];
}

// one block: per-bin prefix over blocks -> bhoff; global bin prefix -> binoff
__global__ void k_binscan(const int* __restrict__ bh, int* __restrict__ bhoff,
                          int* __restrict__ binoff, int nb) {
  int b = threadIdx.x;
  int acc = 0;
  for (int blk = 0; blk < nb; ++blk) {
    int v = bh[blk * 256 + b];
    bhoff[blk * 256 + b] = acc;
    acc += v;
  }
  __shared__ int s[256];
  int v = acc;
  s[b] = v;
  __syncthreads();
  for (int off = 1; off < 256; off <<= 1) {
    int x = (b >= off) ? s[b - off] : 0;
    __syncthreads();
    s[b] += x;
    __syncthreads();
  }
  binoff[b] = s[b] - v;  // exclusive
}

// local ranks via LDS atomics only (per-block, low contention)
__global__ void k_sortscatter2(const int* __restrict__ deg, const int* __restrict__ binoff,
                               const int* __restrict__ bhoff, int* __restrict__ nodemap) {
  __shared__ int h[256];
  int t = threadIdx.x;
  h[t] = 0;
  __syncthreads();
  int i = blockIdx.x * 256 + t;
  int b = 0, r = 0;
  bool ok = i < N_NODES;
  if (ok) {
    b = min(deg[i], 255);
    r = atomicAdd(&h[b], 1);
  }
  __syncthreads();
  if (ok) nodemap[binoff[b] + bhoff[blockIdx.x * 256 + b] + r] = i;
}

// ---------------- W transpose to bf16: Wt[n][k] = bf16(W[k][n]) ----------------
__global__ void k_wt(const float* __restrict__ W, ushort* __restrict__ Wt, int K, int N) {
  int idx = blockIdx.x * 256 + threadIdx.x;
  if (idx >= K * N) return;
  int n = idx / K, k = idx % K;
  Wt[idx] = f2bf(W[(size_t)k * N + n]);
}

// ---------------- bf16 MFMA GEMM: hsc = bf16( f(A) @ W * d_isqrt ), chunk-major ----
template <int D, int CW, bool APPLY_BN>
__global__ __launch_bounds__(256, 2) void k_gemm_bf16(const void* __restrict__ Av,
                                                      const ushort* __restrict__ Wt,
                                                      const float* __restrict__ ss,
                                                      const float* __restrict__ dis,
                                                      ushort* __restrict__ hsc) {
  constexpr int BM = 128, BN = 128, BK = 32, K = 256;
  constexpr int LDP = BK + 8;  // 40 bf16 (80B) stride: conflict-free b128 frags
  __shared__ ushort As[BM * LDP];
  __shared__ ushort Bs[BN * LDP];
  const int tid = threadIdx.x;
  const int lane = tid & 63;
  const int wid = tid >> 6;
  const int wr = wid >> 1, wc = wid & 1;  // 2x2 wave grid
  constexpr int NB = D / BN;
  const int rb = (blockIdx.x / NB) * BM;
  const int cb = (blockIdx.x % NB) * BN;

  f32x4 acc[4][4];
#pragma unroll
  for (int m = 0; m < 4; ++m)
#pragma unroll
    for (int n = 0; n < 4; ++n) acc[m][n] = (f32x4)(0.f);

  for (int kt = 0; kt < K; kt += BK) {
#pragma unroll
    for (int it = 0; it < 2; ++it) {
      int idx = tid + it * 256;
      int row = idx >> 2, kq = idx & 3;
      int gr = rb + row;
      if (gr >= N_NODES) gr = N_NODES - 1;
      float e[8];
      if constexpr (APPLY_BN) {
        const ushort* A = (const ushort*)Av;
        short8 v = *reinterpret_cast<const short8*>(&A[(size_t)gr * K + kt + kq * 8]);
#pragma unroll
        for (int q = 0; q < 8; ++q) {
          int k = kt + kq * 8 + q;
          e[q] = fmaxf(bf2f((ushort)v[q]) * ss[k] + ss[256 + k], 0.f);
        }
      } else {
        const float* A = (const float*)Av;
        const float4* src = reinterpret_cast<const float4*>(&A[(size_t)gr * K + kt + kq * 8]);
        float4 v0 = src[0], v1 = src[1];
        e[0] = v0.x; e[1] = v0.y; e[2] = v0.z; e[3] = v0.w;
        e[4] = v1.x; e[5] = v1.y; e[6] = v1.z; e[7] = v1.w;
      }
      short8 pk;
#pragma unroll
      for (int q = 0; q < 8; ++q) pk[q] = (short)f2bf(e[q]);
      *reinterpret_cast<short8*>(&As[row * LDP + kq * 8]) = pk;
    }
#pragma unroll
    for (int it = 0; it < 2; ++it) {
      int idx = tid + it * 256;
      int n = idx >> 2, kq = idx & 3;
      short8 v = *reinterpret_cast<const short8*>(&Wt[(size_t)(cb + n) * K + kt + kq * 8]);
      *reinterpret_cast<short8*>(&Bs[n * LDP + kq * 8]) = v;
    }
    __syncthreads();

    const int rl = lane & 15;
    const int kb = (lane >> 4) * 8;
    short8 af[4], bfr[4];
#pragma unroll
    for (int f = 0; f < 4; ++f) {
      af[f] = *reinterpret_cast<short8*>(&As[(wr * 64 + f * 16 + rl) * LDP + kb]);
      bfr[f] = *reinterpret_cast<short8*>(&Bs[(wc * 64 + f * 16 + rl) * LDP + kb]);
    }
#pragma unroll
    for (int m = 0; m < 4; ++m)
#pragma unroll
      for (int n = 0; n < 4; ++n)
        acc[m][n] = __builtin_amdgcn_mfma_f32_16x16x32_bf16(af[m], bfr[n], acc[m][n], 0, 0, 0);
    __syncthreads();
  }

  const int cl = lane & 15;
  const int rq = lane >> 4;
#pragma unroll
  for (int m = 0; m < 4; ++m) {
    int rbase = rb + wr * 64 + m * 16 + rq * 4;
#pragma unroll
    for (int j = 0; j < 4; ++j) {
      int row = rbase + j;
      if (row >= N_NODES) continue;
      float di = dis[row];
#pragma unroll
      for (int n = 0; n < 4; ++n) {
        int col = cb + wc * 64 + n * 16 + cl;
        size_t addr = ((size_t)(col / CW) * N_NODES + row) * CW + (col % CW);
        hsc[addr] = f2bf(acc[m][n][j] * di);
      }
    }
  }
}

// ---------------- chunked agg v3: lane owns (node, 4 cols); no reduction ----------
template <int CW, bool OUT_F32, int OUTD>
__global__ __launch_bounds__(256) void k_agg_sorted(const ushort* __restrict__ hsc,
                                                    const int* __restrict__ cs,
                                                    const int* __restrict__ rs,
                                                    const int* __restrict__ nodemap,
                                                    const float* __restrict__ dis,
                                                    const float* __restrict__ bias,
                                                    void* __restrict__ outp) {
  constexpr int LPG = CW / 4;   // lanes per node group: 8 (CW=32) / 4 (CW=16)
  constexpr int NG = 64 / LPG;  // nodes per wave: 8 / 16
  const int chunk = blockIdx.x & 7;
  const int wave = threadIdx.x >> 6;
  const int lane = threadIdx.x & 63;
  const int g = lane / LPG;
  const int k = lane & (LPG - 1);
  const int spos = (blockIdx.x >> 3) * (4 * NG) + wave * NG + g;
  const bool alive = spos < N_NODES;
  const int node = alive ? nodemap[spos] : 0;
  const int s = rs[node];
  const int deg = alive ? (rs[node + 1] - s) : 0;
  const ushort* bc = hsc + (size_t)chunk * N_NODES * CW + k * 4;

  // self contribution
  ushort4 sv = *reinterpret_cast<const ushort4*>(&bc[(size_t)node * CW]);
  float a0 = bf2f(sv.x), a1 = bf2f(sv.y), a2 = bf2f(sv.z), a3 = bf2f(sv.w);

  int jb = 0;
  for (; jb + LPG <= deg; jb += LPG) {
    int idxk = cs[s + jb + k];  // lane k holds index for step k
    ushort4 v[LPG];
#pragma unroll
    for (int st = 0; st < LPG; ++st) {
      int c = __shfl(idxk, g * LPG + st);
      v[st] = *reinterpret_cast<const ushort4*>(&bc[(size_t)((uint)c * CW)]);
    }
#pragma unroll
    for (int st = 0; st < LPG; ++st) {
      a0 += bf2f(v[st].x);
      a1 += bf2f(v[st].y);
      a2 += bf2f(v[st].z);
      a3 += bf2f(v[st].w);
    }
  }
  if (jb < deg) {  // tail batch, weight-folded
    int idxk = (jb + k < deg) ? cs[s + jb + k] : 0;
    ushort4 v[LPG];
#pragma unroll
    for (int st = 0; st < LPG; ++st) {
      int c = __shfl(idxk, g * LPG + st);
      v[st] = *reinterpret_cast<const ushort4*>(&bc[(size_t)((uint)c * CW)]);
    }
#pragma unroll
    for (int st = 0; st < LPG; ++st) {
      float w = (jb + st < deg) ? 1.f : 0.f;
      a0 = fmaf(w, bf2f(v[st].x), a0);
      a1 = fmaf(w, bf2f(v[st].y), a1);
      a2 = fmaf(w, bf2f(v[st].z), a2);
      a3 = fmaf(w, bf2f(v[st].w), a3);
    }
  }

  if (alive) {
    float di = dis[node];
    float4 b = *reinterpret_cast<const float4*>(&bias[chunk * CW + k * 4]);
    float o0 = a0 * di + b.x, o1 = a1 * di + b.y;
    float o2 = a2 * di + b.z, o3 = a3 * di + b.w;
    if constexpr (OUT_F32) {
      float* out = (float*)outp;
      float4 o = {o0, o1, o2, o3};
      *reinterpret_cast<float4*>(&out[(size_t)node * OUTD + chunk * CW + k * 4]) = o;
    } else {
      ushort* out = (ushort*)outp;
      ushort4 o;
      o.x = f2bf(o0);
      o.y = f2bf(o1);
      o.z = f2bf(o2);
      o.w = f2bf(o3);
      *reinterpret_cast<ushort4*>(&out[(size_t)node * OUTD + chunk * CW + k * 4]) = o;
    }
  }
}

// ---------------- log_softmax over D=128 f32 logits (wave per node) ----------------
__global__ __launch_bounds__(256) void k_lsm(const float* __restrict__ pre2,
                                             float* __restrict__ out) {
  int node = (blockIdx.x * 256 + threadIdx.x) >> 6;
  if (node >= N_NODES) return;
  int lane = threadIdx.x & 63;
  float2 v = *reinterpret_cast<const float2*>(&pre2[(size_t)node * 128 + lane * 2]);
  float m = fmaxf(v.x, v.y);
#pragma unroll
  for (int o = 1; o < 64; o <<= 1) m = fmaxf(m, __shfl_xor(m, o));
  float sum = __expf(v.x - m) + __expf(v.y - m);
#pragma unroll
  for (int o = 1; o < 64; o <<= 1) sum += __shfl_xor(sum, o);
  float ls = m + logf(sum);
  float2 o2 = {v.x - ls, v.y - ls};
  *reinterpret_cast<float2*>(&out[(size_t)node * 128 + lane * 2]) = o2;
}

// ---------------- batchnorm stats: three-phase, atomic-free ----------------
__global__ __launch_bounds__(256) void k_bnstatsA(const ushort* __restrict__ pre,
                                                  float* __restrict__ partial) {
  int t = threadIdx.x;
  int rsub = t >> 7;
  int cp = (t & 127) * 2;
  float s0 = 0.f, s1 = 0.f, q0 = 0.f, q1 = 0.f;
  for (int r = blockIdx.x * 2 + rsub; r < N_NODES; r += BNA_BLOCKS * 2) {
    ushort2 v = *reinterpret_cast<const ushort2*>(&pre[(size_t)r * 256 + cp]);
    float f0 = bf2f(v.x), f1 = bf2f(v.y);
    s0 += f0;
    q0 += f0 * f0;
    s1 += f1;
    q1 += f1 * f1;
  }
  __shared__ float lsum[256], lsq[256];
  if (rsub) {
    lsum[cp] = s0;
    lsum[cp + 1] = s1;
    lsq[cp] = q0;
    lsq[cp + 1] = q1;
  }
  __syncthreads();
  if (!rsub) {
    float* p = &partial[(size_t)blockIdx.x * 512];
    p[cp] = s0 + lsum[cp];
    p[cp + 1] = s1 + lsum[cp + 1];
    p[256 + cp] = q0 + lsq[cp];
    p[256 + cp + 1] = q1 + lsq[cp + 1];
  }
}

__global__ __launch_bounds__(512) void k_bnstatsB(const float* __restrict__ partial,
                                                  float* __restrict__ p2) {
  int t = threadIdx.x, b = blockIdx.x;
  float a = 0.f;
#pragma unroll 8
  for (int r = 0; r < BNA_BLOCKS / 8; ++r)
    a += partial[(size_t)(b * (BNA_BLOCKS / 8) + r) * 512 + t];
  p2[(size_t)b * 512 + t] = a;
}

__global__ void k_bnfinal(const float* __restrict__ p2, const float* __restrict__ gamma,
                          const float* __restrict__ beta, float* __restrict__ ss) {
  int t = threadIdx.x;
  float sum = 0.f, sq = 0.f;
#pragma unroll
  for (int b = 0; b < 8; ++b) {
    sum += p2[(size_t)b * 512 + t];
    sq += p2[(size_t)b * 512 + 256 + t];
  }
  float mu = sum * (1.f / N_NODES);
  float var = sq * (1.f / N_NODES) - mu * mu;
  float sc = gamma[t] * rsqrtf(var + BN_EPS);
  ss[t] = sc;
  ss[256 + t] = beta[t] - mu * sc;
}

// ---------------- launcher ----------------
extern "C" void kernel_launch(void* const* d_in, const int* in_sizes, int n_in,
                              void* d_out, int out_size, void* d_ws, size_t ws_size,
                              hipStream_t stream) {
  const float* x = (const float*)d_in[0];
  const int* erow = (const int*)d_in[1];
  const int* ecol = erow + N_EDGES;
  const float* W0 = (const float*)d_in[2];
  const float* b0 = (const float*)d_in[3];
  const float* W1 = (const float*)d_in[4];
  const float* b1 = (const float*)d_in[5];
  const float* W2 = (const float*)d_in[6];
  const float* b2 = (const float*)d_in[7];
  const float* g0 = (const float*)d_in[8];
  const float* be0 = (const float*)d_in[9];
  const float* g1 = (const float*)d_in[10];
  const float* be1 = (const float*)d_in[11];
  float* out = (float*)d_out;

  char* ws = (char*)d_ws;
  size_t off = 0;
  auto take = [&](size_t bytes) {
    char* p = ws + off;
    off = (off + bytes + 255) & ~(size_t)255;
    return p;
  };
  int* deg = (int*)take(N_NODES * 4);
  int* fill = (int*)take(N_NODES * 4);
  size_t zero_bytes = off;  // deg/fill must start at 0 each call
  int nb = (N_NODES + 255) / 256;  // 196
  int* bh = (int*)take((size_t)nb * 256 * 4);
  int* bhoff = (int*)take((size_t)nb * 256 * 4);
  int* binoff = (int*)take(256 * 4);
  int* nodemap = (int*)take(N_NODES * 4);
  float* bnpart = (float*)take((size_t)BNA_BLOCKS * 512 * 4);
  float* bnpart2 = (float*)take(8 * 512 * 4);
  float* dis = (float*)take(N_NODES * 4);
  int* row_start = (int*)take((N_NODES + 1) * 4);
  int* bsum = (int*)take(256 * 4);
  int* boff = (int*)take(256 * 4);
  float* ss0 = (float*)take(512 * 4);
  float* ss1 = (float*)take(512 * 4);
  ushort* Wt0 = (ushort*)take(256 * 256 * 2);
  ushort* Wt1 = (ushort*)take(256 * 256 * 2);
  ushort* Wt2 = (ushort*)take(256 * 128 * 2);
  int* col_sorted = (int*)take((size_t)N_EDGES * 4);
  ushort* hsc = (ushort*)take((size_t)N_NODES * 256 * 2);   // chunk-major
  ushort* pre = (ushort*)take((size_t)N_NODES * 256 * 2);   // row-major bf16
  float* pre2 = (float*)take((size_t)N_NODES * 128 * 4);    // f32 logits
  if (off > ws_size) return;

  hipMemsetAsync(d_ws, 0, zero_bytes, stream);

  k_deg<<<1024, 256, 0, stream>>>(erow, deg);
  k_disqrt<<<(N_NODES + 255) / 256, 256, 0, stream>>>(deg, dis);
  k_scan_part<<<nb, 256, 0, stream>>>(deg, bsum);
  k_scan_top<<<1, 256, 0, stream>>>(bsum, boff, nb);
  k_scan_final<<<nb, 256, 0, stream>>>(deg, boff, row_start);
  k_scatter<<<1024, 256, 0, stream>>>(erow, ecol, row_start, fill, col_sorted);

  // degree sort (stable two-level counting sort, no global atomics)
  k_blockhist<<<nb, 256, 0, stream>>>(deg, bh);
  k_binscan<<<1, 256, 0, stream>>>(bh, bhoff, binoff, nb);
  k_sortscatter2<<<nb, 256, 0, stream>>>(deg, binoff, bhoff, nodemap);

  k_wt<<<(256 * 256 + 255) / 256, 256, 0, stream>>>(W0, Wt0, 256, 256);
  k_wt<<<(256 * 256 + 255) / 256, 256, 0, stream>>>(W1, Wt1, 256, 256);
  k_wt<<<(256 * 128 + 255) / 256, 256, 0, stream>>>(W2, Wt2, 256, 128);

  int mblocks = (N_NODES + 127) / 128;                 // 391
  int agg32_grid = ((N_NODES + 31) / 32) * 8;          // 12504
  int agg16_grid = ((N_NODES + 63) / 64) * 8;          // 6256
  int lsm_grid = (N_NODES * 64 + 255) / 256;           // 12500
  // layer 0
  k_gemm_bf16<256, 32, false><<<mblocks * 2, 256, 0, stream>>>(x, Wt0, nullptr, dis, hsc);
  k_agg_sorted<32, false, 256><<<agg32_grid, 256, 0, stream>>>(hsc, col_sorted, row_start, nodemap, dis, b0, pre);
  k_bnstatsA<<<BNA_BLOCKS, 256, 0, stream>>>(pre, bnpart);
  k_bnstatsB<<<8, 512, 0, stream>>>(bnpart, bnpart2);
  k_bnfinal<<<1, 256, 0, stream>>>(bnpart2, g0, be0, ss0);
  // layer 1
  k_gemm_bf16<256, 32, true><<<mblocks * 2, 256, 0, stream>>>(pre, Wt1, ss0, dis, hsc);
  k_agg_sorted<32, false, 256><<<agg32_grid, 256, 0, stream>>>(hsc, col_sorted, row_start, nodemap, dis, b1, pre);
  k_bnstatsA<<<BNA_BLOCKS, 256, 0, stream>>>(pre, bnpart);
  k_bnstatsB<<<8, 512, 0, stream>>>(bnpart, bnpart2);
  k_bnfinal<<<1, 256, 0, stream>>>(bnpart2, g1, be1, ss1);
  // layer 2: GEMM -> chunked agg (f32 logits) -> log_softmax
  k_gemm_bf16<128, 16, true><<<mblocks, 256, 0, stream>>>(pre, Wt2, ss1, dis, hsc);
  k_agg_sorted<16, true, 128><<<agg16_grid, 256, 0, stream>>>(hsc, col_sorted, row_start, nodemap, dis, b2, pre2);
  k_lsm<<<lsm_grid, 256, 0, stream>>>(pre2, out);
}